// Round 3
// baseline (8887.545 us; speedup 1.0000x reference)
//
#include <hip/hip_runtime.h>

// ---------------------------------------------------------------------------
// StackedBidirectionalLstm  (B=32, T=512, IN=512, H=512, LAYERS=2, bidir, highway)
//
// Round 3: replace 1024 per-step launches with 2 persistent kernels (one per
// layer), grid-synced via a device-scope per-step barrier. Wh fragments live
// in VGPRs for the whole layer; c lives in 2 registers/thread; px repacked
// t-major so each step reads contiguous memory.
//
//   ws layout (bytes), total ~202.1 MiB:
//     px   @ 0          201,326,592  ([2][512*32][3072] bf16, t-major)
//     whp  @ 201326592   10,485,760  (packed Wh fragments, 4 x 1,310,720 elems)
//     hbf  @ 211812352      131,072  (2 buf x 2 dir x 32 x 512 bf16)
//     bar  @ 211943424        4,096  (1024 u32 barrier slots)
//   d_out scratch:
//     phase A: xbf @ +0 (16 MiB), wxt0 @ +16 MiB (6 MiB), wxt1 @ +32 MiB (12 MiB)
//     phase B: a1bf @ +0 (32 MiB); layer-1 persist overwrites d_out with y.
// ---------------------------------------------------------------------------

typedef float f32x4 __attribute__((ext_vector_type(4)));
typedef __bf16 bf16x8 __attribute__((ext_vector_type(8)));
typedef unsigned short us8 __attribute__((ext_vector_type(8)));
typedef unsigned short us4 __attribute__((ext_vector_type(4)));

__device__ __forceinline__ unsigned short f2bf(float f) {
  unsigned int u = __float_as_uint(f);
  u += 0x7FFFu + ((u >> 16) & 1u);            // round-to-nearest-even
  return (unsigned short)(u >> 16);
}
__device__ __forceinline__ float bf2f(unsigned short h) {
  return __uint_as_float(((unsigned int)h) << 16);
}
__device__ __forceinline__ float sigf(float x) { return 1.0f / (1.0f + __expf(-x)); }
__device__ __forceinline__ float tanh_(float x) { return 2.0f / (1.0f + __expf(-2.0f * x)) - 1.0f; }

#define MFMA(a, b, c) __builtin_amdgcn_mfma_f32_16x16x32_bf16((a), (b), (c), 0, 0, 0)
#define GLOAD_LDS(gp, lp)                                                           \
  __builtin_amdgcn_global_load_lds(                                                 \
      (const __attribute__((address_space(1))) void*)(gp),                          \
      (__attribute__((address_space(3))) void*)(lp), 16, 0, 0)

// --------------------------- prep kernels ----------------------------------

__global__ void k_convert_x(const float* __restrict__ x, unsigned short* __restrict__ xb, int n4) {
  int i = blockIdx.x * blockDim.x + threadIdx.x;
  if (i < n4) {
    float4 v = ((const float4*)x)[i];
    us4 o;
    o[0] = f2bf(v.x); o[1] = f2bf(v.y); o[2] = f2bf(v.z); o[3] = f2bf(v.w);
    ((us4*)xb)[i] = o;
  }
}

// Tiled transpose: WxT[n][k] = bf16(Wx[k][n]); z = layer*2+dir
__global__ __launch_bounds__(256) void k_pack_wxT(
    const float* __restrict__ W0, const float* __restrict__ W1,
    const float* __restrict__ W2, const float* __restrict__ W3,
    unsigned short* __restrict__ o01, unsigned short* __restrict__ o23) {
  int y = blockIdx.z;
  int K = (y >> 1) ? 1024 : 512;
  int kb = blockIdx.y * 32;
  if (kb >= K) return;
  const float* W = (y == 0) ? W0 : (y == 1) ? W1 : (y == 2) ? W2 : W3;
  unsigned short* o = (y >> 1) ? (o23 + (size_t)(y & 1) * 3072 * 1024)
                               : (o01 + (size_t)(y & 1) * 3072 * 512);
  __shared__ float tile[32][33];
  int nb = blockIdx.x * 32;
  int tx = threadIdx.x & 31, ty = threadIdx.x >> 5;   // ty 0..7
#pragma unroll
  for (int r = 0; r < 4; ++r)
    tile[ty + r * 8][tx] = W[(size_t)(kb + ty + r * 8) * 3072 + nb + tx];
  __syncthreads();
#pragma unroll
  for (int r = 0; r < 4; ++r)
    o[(size_t)(nb + ty + r * 8) * K + kb + tx] = f2bf(tile[tx][ty + r * 8]);
}

// Pack Wh (512x2560 f32) into MFMA B-fragments:
// out[(((g*32+ns)*16+ks)*64+lane)*8+e] = Wh[ks*32+(lane>>4)*8+e][g*512+ns*16+(lane&15)]
__global__ void k_pack_whp(const float* __restrict__ W0, const float* __restrict__ W1,
                           const float* __restrict__ W2, const float* __restrict__ W3,
                           unsigned short* __restrict__ out) {
  int y = blockIdx.y;
  const float* W = (y == 0) ? W0 : (y == 1) ? W1 : (y == 2) ? W2 : W3;
  unsigned short* o = out + (size_t)y * 1310720;
  int v = blockIdx.x * 256 + threadIdx.x;   // < 163840
  int lane = v & 63, ks = (v >> 6) & 15, ns = (v >> 10) & 31, g = v >> 15;
  int col = g * 512 + ns * 16 + (lane & 15);
  int kb = ks * 32 + ((lane >> 4) << 3);
  us8 vec;
#pragma unroll
  for (int e = 0; e < 8; ++e) vec[e] = f2bf(W[(size_t)(kb + e) * 2560 + col]);
  *(us8*)&o[(size_t)v * 8] = vec;
}

// --------------------------- bf16 GEMM -------------------------------------
// px[rr][col] with rr = t*32+b (t-major), from A[16384][K] @ Bt[3072][K]^T.
__global__ __launch_bounds__(256) void k_gemm(const unsigned short* __restrict__ A,
                                              const unsigned short* __restrict__ BtBase,
                                              unsigned short* __restrict__ CBase, int K) {
  __shared__ __align__(128) unsigned short As[128 * 32];
  __shared__ __align__(128) unsigned short Bs[128 * 32];
  const unsigned short* Bt = BtBase + (size_t)blockIdx.z * 3072 * K;
  unsigned short* C = CBase + (size_t)blockIdx.z * 16384 * 3072;
  int tid = threadIdx.x;
  int w = tid >> 6, l = tid & 63;
  int m0 = blockIdx.x * 128, n0 = blockIdx.y * 128;
  int wr = (w >> 1) * 64, wc = (w & 1) * 64;
  f32x4 acc[4][4];
#pragma unroll
  for (int i = 0; i < 4; ++i)
#pragma unroll
    for (int j = 0; j < 4; ++j) acc[i][j] = (f32x4){0.f, 0.f, 0.f, 0.f};

  for (int k0 = 0; k0 < K; k0 += 32) {
    __syncthreads();
#pragma unroll
    for (int half = 0; half < 2; ++half) {
      int r = w * 32 + half * 16 + (l >> 2);     // row within tile
      int gq = (l & 3) ^ (r & 3);                // swizzled source quarter
      GLOAD_LDS(A + (size_t)(m0 + r) * K + k0 + gq * 8, &As[(w * 32 + half * 16) * 32]);
      GLOAD_LDS(Bt + (size_t)(n0 + r) * K + k0 + gq * 8, &Bs[(w * 32 + half * 16) * 32]);
    }
    __syncthreads();
    bf16x8 af[4], bfr[4];
#pragma unroll
    for (int mi = 0; mi < 4; ++mi) {
      int r = wr + mi * 16 + (l & 15);
      int q = (l >> 4) ^ (r & 3);
      af[mi] = __builtin_bit_cast(bf16x8, *(const us8*)&As[r * 32 + q * 8]);
    }
#pragma unroll
    for (int ni = 0; ni < 4; ++ni) {
      int r = wc + ni * 16 + (l & 15);
      int q = (l >> 4) ^ (r & 3);
      bfr[ni] = __builtin_bit_cast(bf16x8, *(const us8*)&Bs[r * 32 + q * 8]);
    }
#pragma unroll
    for (int mi = 0; mi < 4; ++mi)
#pragma unroll
      for (int ni = 0; ni < 4; ++ni) acc[mi][ni] = MFMA(af[mi], bfr[ni], acc[mi][ni]);
  }
#pragma unroll
  for (int mi = 0; mi < 4; ++mi)
#pragma unroll
    for (int ni = 0; ni < 4; ++ni)
#pragma unroll
      for (int r4 = 0; r4 < 4; ++r4) {
        int row = m0 + wr + mi * 16 + (l >> 4) * 4 + r4;    // b*512 + t
        int rr = ((row & 511) << 5) + (row >> 9);           // t*32 + b
        int col = n0 + wc + ni * 16 + (l & 15);
        C[(size_t)rr * 3072 + col] = f2bf(acc[mi][ni][r4]);
      }
}

// --------------------------- persistent LSTM layer -------------------------
// 64 WGs x 256 threads, all co-resident (256 CUs). WG = (dir d, slice ns).
// Grid barrier per step via device-scope atomics + threadfence.
__global__ __launch_bounds__(256, 1) void k_persist(
    const unsigned short* __restrict__ px,    // [2][512*32][3072] bf16 t-major
    const unsigned short* __restrict__ wp,    // this layer: [2 dir][5][32][16][512]
    const float* __restrict__ bias_f, const float* __restrict__ bias_b,
    unsigned short* __restrict__ hbf,         // [2 buf][2 dir][32][512] bf16
    unsigned short* __restrict__ ybf,         // layer0: a1bf, else null
    float* __restrict__ yf,                   // layer1: d_out, else null
    float* __restrict__ finals,               // d_out + 16777216
    unsigned int* __restrict__ bar, int layer) {
  __shared__ float part[4][32][80];           // 40 KiB
  int wg = blockIdx.x;
  int d = wg >> 5, ns = wg & 31, j0 = ns * 16;
  int tid = threadIdx.x;
  int w = tid >> 6, l = tid & 63;
  const unsigned short* wpd = wp + (size_t)d * 1310720;
  const unsigned short* pxd = px + (size_t)d * 16384 * 3072;
  const float* bias = d ? bias_b : bias_f;

  // ---- per-thread constants (epilogue mapping: idx = tid, tid+256) ----
  int j = tid & 15, jg = j0 + j;
  int b0 = tid >> 4, b1 = b0 + 16;

  // ---- load Wh fragment slice into VGPRs (once per layer) ----
  bf16x8 wf[5][4];
#pragma unroll
  for (int g = 0; g < 5; ++g)
#pragma unroll
    for (int kk = 0; kk < 4; ++kk)
      wf[g][kk] = __builtin_bit_cast(
          bf16x8, *(const us8*)&wpd[(size_t)((g * 32 + ns) * 16 + (w * 4 + kk)) * 512 + l * 8]);

  float bv[5];
#pragma unroll
  for (int g = 0; g < 5; ++g) bv[g] = bias[(g << 9) + jg];

  float c0 = 0.f, c1 = 0.f;                  // cell state lives in registers
  unsigned short xv0[6], xv1[6];             // px prefetch

  // prefetch px for s=0
  {
    int t = d ? 511 : 0;
    const unsigned short* pp0 = pxd + ((size_t)((t << 5) + b0)) * 3072 + jg;
    const unsigned short* pp1 = pxd + ((size_t)((t << 5) + b1)) * 3072 + jg;
#pragma unroll
    for (int q = 0; q < 6; ++q) { xv0[q] = pp0[q << 9]; xv1[q] = pp1[q << 9]; }
  }

  for (int s = 0; s < 512; ++s) {
    int t = d ? (511 - s) : s;
    const unsigned short* hb = hbf + (size_t)(((s & 1) << 1) + d) * 16384;
    unsigned short* ho = hbf + (size_t)((((s + 1) & 1) << 1) + d) * 16384;

    // ---- ps = h @ Wh (MFMA, K-split over 4 waves) ----
    f32x4 acc[2][5];
#pragma unroll
    for (int m = 0; m < 2; ++m)
#pragma unroll
      for (int g = 0; g < 5; ++g) acc[m][g] = (f32x4){0.f, 0.f, 0.f, 0.f};
#pragma unroll
    for (int kk = 0; kk < 4; ++kk) {
      int k0 = ((w * 4 + kk) << 5) + ((l >> 4) << 3);
      bf16x8 a0 = __builtin_bit_cast(bf16x8, *(const us8*)&hb[(l & 15) * 512 + k0]);
      bf16x8 a1 = __builtin_bit_cast(bf16x8, *(const us8*)&hb[((l & 15) + 16) * 512 + k0]);
#pragma unroll
      for (int g = 0; g < 5; ++g) {
        acc[0][g] = MFMA(a0, wf[g][kk], acc[0][g]);
        acc[1][g] = MFMA(a1, wf[g][kk], acc[1][g]);
      }
    }
#pragma unroll
    for (int m = 0; m < 2; ++m)
#pragma unroll
      for (int g = 0; g < 5; ++g)
#pragma unroll
        for (int r4 = 0; r4 < 4; ++r4)
          part[w][m * 16 + (l >> 4) * 4 + r4][g * 16 + (l & 15)] = acc[m][g][r4];
    __syncthreads();

    // ---- gates / state / outputs (2 rows per thread) ----
#pragma unroll
    for (int p = 0; p < 2; ++p) {
      int bb = p ? b1 : b0;
      const unsigned short* xv = p ? xv1 : xv0;
      float ps_[5];
#pragma unroll
      for (int g = 0; g < 5; ++g) {
        int cc = g * 16 + j;
        ps_[g] = part[0][bb][cc] + part[1][bb][cc] + part[2][bb][cc] + part[3][bb][cc] + bv[g];
      }
      float x0 = bf2f(xv[0]), x1 = bf2f(xv[1]), x2 = bf2f(xv[2]);
      float x3 = bf2f(xv[3]), x4 = bf2f(xv[4]), x5 = bf2f(xv[5]);
      float iG = sigf(x0 + ps_[0]);
      float fG = sigf(x1 + ps_[1]);
      float gG = tanh_(x2 + ps_[2]);
      float oG = sigf(x3 + ps_[3]);
      float cp = p ? c1 : c0;
      float cn = iG * gG + fG * cp;
      if (p) c1 = cn; else c0 = cn;
      float ht = oG * tanh_(cn);
      float rG = sigf(x4 + ps_[4]);
      ht = rG * ht + (1.f - rG) * x5;
      ho[bb * 512 + jg] = f2bf(ht);
      size_t yo = ((size_t)(bb * 512 + t)) * 1024 + d * 512 + jg;
      if (ybf) ybf[yo] = f2bf(ht);
      else     yf[yo] = ht;
      if (s == 511) {
        int fo = (layer * 32 + bb) * 1024 + d * 512 + jg;
        finals[fo] = ht;            // final_h
        finals[65536 + fo] = cn;    // final_c
      }
    }

    if (s == 511) break;

    // ---- prefetch px for s+1 (independent of h; hides under barrier) ----
    {
      int tn = d ? (511 - (s + 1)) : (s + 1);
      const unsigned short* pp0 = pxd + ((size_t)((tn << 5) + b0)) * 3072 + jg;
      const unsigned short* pp1 = pxd + ((size_t)((tn << 5) + b1)) * 3072 + jg;
#pragma unroll
      for (int q = 0; q < 6; ++q) { xv0[q] = pp0[q << 9]; xv1[q] = pp1[q << 9]; }
    }

    // ---- grid barrier (device-scope; all 64 WGs co-resident) ----
    __syncthreads();
    if (tid == 0) {
      __threadfence();    // release: flush h stores to coherent point
      unsigned int* slot = &bar[layer * 512 + s];
      __hip_atomic_fetch_add(slot, 1u, __ATOMIC_RELAXED, __HIP_MEMORY_SCOPE_AGENT);
      unsigned int v;
      long guard = 0;
      do {
        v = __hip_atomic_load(slot, __ATOMIC_RELAXED, __HIP_MEMORY_SCOPE_AGENT);
      } while (v < 64u && ++guard < 2000000L);
      __threadfence();    // acquire: invalidate stale cached h
    }
    __syncthreads();
  }
}

// --------------------------- host ------------------------------------------

extern "C" void kernel_launch(void* const* d_in, const int* in_sizes, int n_in,
                              void* d_out, int out_size, void* d_ws, size_t ws_size,
                              hipStream_t stream) {
  (void)in_sizes; (void)n_in; (void)out_size; (void)ws_size;
  const float* x = (const float*)d_in[0];
  const float* Wx[4] = {(const float*)d_in[1], (const float*)d_in[4],
                        (const float*)d_in[7], (const float*)d_in[10]};
  const float* Wh[4] = {(const float*)d_in[2], (const float*)d_in[5],
                        (const float*)d_in[8], (const float*)d_in[11]};
  const float* bs[4] = {(const float*)d_in[3], (const float*)d_in[6],
                        (const float*)d_in[9], (const float*)d_in[12]};

  // ws: px + packed Wh + h double-buffer + barrier slots (~202.1 MiB)
  char* ws = (char*)d_ws;
  unsigned short* px   = (unsigned short*)(ws);
  unsigned short* whp  = (unsigned short*)(ws + 201326592);
  unsigned short* hbf  = (unsigned short*)(ws + 211812352);
  unsigned int*   bar  = (unsigned int*)(ws + 211943424);

  // d_out doubles as scratch for transients (all dead before final y writes)
  char* ob = (char*)d_out;
  unsigned short* xbf  = (unsigned short*)(ob);             // 16 MiB, phase A
  unsigned short* wxt0 = (unsigned short*)(ob + 16777216);  // 6 MiB, phase A
  unsigned short* wxt1 = (unsigned short*)(ob + 33554432);  // 12 MiB
  unsigned short* a1bf = (unsigned short*)(ob);             // 32 MiB, phase B
  float* out = (float*)d_out;
  float* finals = out + 16777216;

  k_convert_x<<<8192, 256, 0, stream>>>(x, xbf, 2097152);
  k_pack_wxT<<<dim3(96, 32, 4), 256, 0, stream>>>(Wx[0], Wx[1], Wx[2], Wx[3], wxt0, wxt1);
  k_pack_whp<<<dim3(640, 4), 256, 0, stream>>>(Wh[0], Wh[1], Wh[2], Wh[3], whp);
  hipMemsetAsync(bar, 0, 4096, stream);

  for (int layer = 0; layer < 2; ++layer) {
    int K = layer ? 1024 : 512;
    const unsigned short* Ag = layer ? a1bf : xbf;
    const unsigned short* wxt = layer ? wxt1 : wxt0;
    k_gemm<<<dim3(128, 24, 2), 256, 0, stream>>>(Ag, wxt, px, K);
    hipMemsetAsync(hbf, 0, 131072, stream);   // zero both h double-buffers
    k_persist<<<64, 256, 0, stream>>>(
        px, whp + (size_t)layer * 2621440, bs[layer * 2], bs[layer * 2 + 1],
        hbf, layer ? nullptr : a1bf, layer ? out : nullptr, finals, bar, layer);
  }
}